// Round 8
// baseline (100.033 us; speedup 1.0000x reference)
//
#include <hip/hip_runtime.h>
#include <hip/hip_bf16.h>

#define IN_F   4096
#define OUT_F  4096
#define BATCH  256

#define BN      16                 // out-features per block
#define BK      64                 // K per step
#define KSPLIT  4                  // K-split factor (grid = 256*KSPLIT)
#define KLEN    (IN_F / KSPLIT)    // 1024 K per block
#define NKS     (KLEN / BK)        // 16 steps per block

typedef __attribute__((ext_vector_type(8))) short shortx8;    // 8 bf16
typedef __attribute__((ext_vector_type(4))) float floatx4;
typedef __attribute__((ext_vector_type(4))) unsigned short ushortx4;

static __device__ __forceinline__ ushort f2bf(float f) {
    union { float f; unsigned int u; } v; v.f = f;
    unsigned int u = v.u;
    u += 0x7FFFu + ((u >> 16) & 1u);   // RNE
    return (ushort)(u >> 16);
}

static __device__ __forceinline__ float softplus_fast(float x) {
    return (x > 15.f) ? x : __logf(1.f + __expf(x));
}

#define KL_C0 (-2.80258509299f)   // log(0.1) - 0.5  (prior_sigma=0.1, prior_mu=0: spec constants)

// sample 4 weights -> bf16 LDS write (8B, swizzled dst), accumulate KL
static __device__ __forceinline__ void sample4(floatx4 m4, floatx4 r4, floatx4 e4,
                                               char* dst, float& kl) {
    ushort w[4];
#pragma unroll
    for (int j = 0; j < 4; ++j) {
        float sig = softplus_fast(r4[j]);
        w[j] = f2bf(fmaf(sig, e4[j], m4[j]));
        kl += fmaf(50.f, fmaf(sig, sig, m4[j] * m4[j]), KL_C0 - __logf(sig));
    }
    ushortx4 pk = { w[0], w[1], w[2], w[3] };
    *(ushortx4*)dst = pk;
}

// ---------------- Kernel A: x f32 -> bf16 -----------------------------------
__global__ __launch_bounds__(256) void xconv_kernel(
    const float* __restrict__ x, ushort* __restrict__ xb)
{
    int i = blockIdx.x * blockDim.x + threadIdx.x;   // over (BATCH*IN_F)/4
    float4 v = ((const float4*)x)[i];
    ushortx4 o = { f2bf(v.x), f2bf(v.y), f2bf(v.z), f2bf(v.w) };
    ((ushortx4*)xb)[i] = o;
}

// ---------------- Kernel B: fused sample + KL + partial GEMM -----------------
// Block (bx, kz): out-rows n0..n0+15, K-range [kz*KLEN, (kz+1)*KLEN).
// Params (mu/rho/eps) read exactly once chip-wide (NT), sampled in-block.
// x (bf16, 2 MB, L2-resident) read per-lane in MFMA fragment layout — no A LDS.
// LDS: only B tile (16x64 bf16), double-buffered, XOR-swizzled; 1 barrier/step.
// Param regs prefetched 2 steps deep (two named sets; loop fully unrolled).
__global__ __launch_bounds__(256, 4) void fused_kernel(
    const ushort* __restrict__ xb,
    const float* __restrict__ mu, const float* __restrict__ rho,
    const float* __restrict__ eps,
    float* __restrict__ Cpart, float* __restrict__ partials)
{
    __shared__ ushort Bl[2][BN * BK];   // 2 x 2 KB

    const int tid  = threadIdx.x;
    const int w    = tid >> 6;
    const int lane = tid & 63;
    const int lr   = lane & 15;
    const int hi   = lane >> 4;
    const int lx   = lr & 7;
    const int bx   = blockIdx.x & 255;
    const int kz   = blockIdx.x >> 8;
    const int n0   = bx * BN;
    const int kb   = kz * KLEN;

    // ---- param addressing: thread -> (row = tid>>4, k4 = (tid&15)*4) ----
    const int prow = tid >> 4;
    const float* muP  = mu  + (size_t)(n0 + prow) * IN_F + kb + (tid & 15) * 4;
    const float* rhoP = rho + (size_t)(n0 + prow) * IN_F + kb + (tid & 15) * 4;
    const float* epsP = eps + (size_t)(n0 + prow) * IN_F + kb + (tid & 15) * 4;
    const int BwrOff = prow * 128 + ((((tid & 15) >> 1) ^ (prow & 7)) << 4) + (tid & 1) * 8;

    // ---- A addressing: lane-direct global reads in fragment layout ----
    // af(mt,s) = 8 bf16 at row w*64+mt*16+lr, k = kb + t*64 + s*32 + hi*8
    const ushort* Arow = xb + (size_t)(w * 64 + lr) * IN_F + kb + hi * 8;

    floatx4 acc[4] = {};
    float kl = 0.f;

    // ---- prologue: sample step 0; prefetch params for steps 1 and 2 ----
    floatx4 P0m, P0r, P0e, P1m, P1r, P1e;
    {
        floatx4 m0 = __builtin_nontemporal_load((const floatx4*)muP);
        floatx4 r0 = __builtin_nontemporal_load((const floatx4*)rhoP);
        floatx4 e0 = __builtin_nontemporal_load((const floatx4*)epsP);
        sample4(m0, r0, e0, (char*)&Bl[0][0] + BwrOff, kl);
    }
    P1m = __builtin_nontemporal_load((const floatx4*)(muP  + BK));      // step 1 (parity 1)
    P1r = __builtin_nontemporal_load((const floatx4*)(rhoP + BK));
    P1e = __builtin_nontemporal_load((const floatx4*)(epsP + BK));
    P0m = __builtin_nontemporal_load((const floatx4*)(muP  + 2 * BK));  // step 2 (parity 0)
    P0r = __builtin_nontemporal_load((const floatx4*)(rhoP + 2 * BK));
    P0e = __builtin_nontemporal_load((const floatx4*)(epsP + 2 * BK));
    __syncthreads();

#pragma unroll
    for (int t = 0; t < NKS; ++t) {
        // ---- compute step t from Bl[t&1] + direct-global A ----
        const ushort* At = Arow + t * BK;
        char* Bb = (char*)&Bl[t & 1][0];
#pragma unroll
        for (int s = 0; s < 2; ++s) {
            const int cs = (((s * 4 + hi) ^ lx) << 4);
            shortx8 bfr = *(const shortx8*)(Bb + lr * 128 + cs);
#pragma unroll
            for (int mt = 0; mt < 4; ++mt) {
                shortx8 af = *(const shortx8*)(At + (size_t)mt * 16 * IN_F + s * 32);
                acc[mt] = __builtin_amdgcn_mfma_f32_16x16x32_bf16(af, bfr, acc[mt], 0, 0, 0);
            }
        }
        // ---- sample step t+1 into other buffer; refill its reg set for t+3 ----
        if (t + 1 < NKS) {
            if (((t + 1) & 1) == 1) {
                sample4(P1m, P1r, P1e, (char*)&Bl[1][0] + BwrOff, kl);
                if (t + 3 < NKS) {
                    P1m = __builtin_nontemporal_load((const floatx4*)(muP  + (t + 3) * BK));
                    P1r = __builtin_nontemporal_load((const floatx4*)(rhoP + (t + 3) * BK));
                    P1e = __builtin_nontemporal_load((const floatx4*)(epsP + (t + 3) * BK));
                }
            } else {
                sample4(P0m, P0r, P0e, (char*)&Bl[0][0] + BwrOff, kl);
                if (t + 3 < NKS) {
                    P0m = __builtin_nontemporal_load((const floatx4*)(muP  + (t + 3) * BK));
                    P0r = __builtin_nontemporal_load((const floatx4*)(rhoP + (t + 3) * BK));
                    P0e = __builtin_nontemporal_load((const floatx4*)(epsP + (t + 3) * BK));
                }
            }
        }
        __syncthreads();   // B[t+1] writes visible; everyone done reading B[t]
    }

    // ---- epilogue: partial-C store (no bias here) ----
    {
        float* Cp = Cpart + (size_t)kz * BATCH * OUT_F;
#pragma unroll
        for (int mt = 0; mt < 4; ++mt) {
            const int mbase = w * 64 + mt * 16 + hi * 4;
#pragma unroll
            for (int q2 = 0; q2 < 4; ++q2)
                Cp[(size_t)(mbase + q2) * OUT_F + n0 + lr] = acc[mt][q2];
        }
    }

    // ---- KL: wave reduce then block reduce -> one partial per block ----
#pragma unroll
    for (int off = 32; off; off >>= 1) kl += __shfl_down(kl, off);
    __shared__ float wsum[4];
    if (lane == 0) wsum[w] = kl;
    __syncthreads();
    if (tid == 0)
        partials[blockIdx.x] = wsum[0] + wsum[1] + wsum[2] + wsum[3];
}

// ---------------- Kernel C: combine partials + bias --------------------------
__global__ __launch_bounds__(256) void combine_kernel(
    const float* __restrict__ Cpart,
    const float* __restrict__ bias_mu, const float* __restrict__ bias_rho,
    const float* __restrict__ eps_b, float* __restrict__ out)
{
    const int i  = blockIdx.x * 256 + threadIdx.x;   // float4 index over 1M/4
    const size_t NP = (size_t)BATCH * OUT_F;
    floatx4 s = ((const floatx4*)Cpart)[i];
    s += ((const floatx4*)(Cpart + NP))[i];
    s += ((const floatx4*)(Cpart + 2 * NP))[i];
    s += ((const floatx4*)(Cpart + 3 * NP))[i];
    const int o = (i * 4) & (OUT_F - 1);
    floatx4 bm = *(const floatx4*)(bias_mu + o);
    floatx4 br = *(const floatx4*)(bias_rho + o);
    floatx4 be = *(const floatx4*)(eps_b + o);
    floatx4 r;
#pragma unroll
    for (int j = 0; j < 4; ++j)
        r[j] = s[j] + fmaf(softplus_fast(br[j]), be[j], bm[j]);
    ((floatx4*)out)[i] = r;
}

// ---------------- Kernel D: final KL reduction (1024 partials) ---------------
__global__ __launch_bounds__(256) void kl_reduce_kernel(
    const float* __restrict__ partials, float* __restrict__ kl_out)
{
    float s = partials[threadIdx.x] + partials[threadIdx.x + 256]
            + partials[threadIdx.x + 512] + partials[threadIdx.x + 768];
#pragma unroll
    for (int off = 32; off; off >>= 1) s += __shfl_down(s, off);
    __shared__ float wsum[4];
    if ((threadIdx.x & 63) == 0) wsum[threadIdx.x >> 6] = s;
    __syncthreads();
    if (threadIdx.x == 0)
        *kl_out = wsum[0] + wsum[1] + wsum[2] + wsum[3];
}

extern "C" void kernel_launch(void* const* d_in, const int* in_sizes, int n_in,
                              void* d_out, int out_size, void* d_ws, size_t ws_size,
                              hipStream_t stream) {
    const float* x     = (const float*)d_in[0];
    const float* w_mu  = (const float*)d_in[1];
    const float* w_rho = (const float*)d_in[2];
    const float* b_mu  = (const float*)d_in[3];
    const float* b_rho = (const float*)d_in[4];
    const float* eps_w = (const float*)d_in[5];
    const float* eps_b = (const float*)d_in[6];
    // d_in[7]=prior_mu (zeros), d_in[8]=prior_sigma (0.1): folded constants.

    float* out = (float*)d_out;
    const size_t KL_IDX = (size_t)BATCH * OUT_F;

    ushort* x_bf     = (ushort*)d_ws;                                    // 2 MB
    float*  Cpart    = (float*)((char*)d_ws + (size_t)BATCH * IN_F * 2); // 16 MB
    float*  partials = (float*)((char*)Cpart
                         + (size_t)KSPLIT * BATCH * OUT_F * 4);          // 4 KB

    // x -> bf16
    xconv_kernel<<<(BATCH * IN_F / 4) / 256, 256, 0, stream>>>(x, x_bf);
    // fused sample + KL + partial GEMM (grid 1024 = 4 blocks/CU)
    fused_kernel<<<256 * KSPLIT, 256, 0, stream>>>(
        x_bf, w_mu, w_rho, eps_w, Cpart, partials);
    // combine K-partials + bias
    combine_kernel<<<(BATCH * OUT_F / 4) / 256, 256, 0, stream>>>(
        Cpart, b_mu, b_rho, eps_b, out);
    // final KL
    kl_reduce_kernel<<<1, 256, 0, stream>>>(partials, out + KL_IDX);
}

// Round 9
// 72.719 us; speedup vs baseline: 1.3756x; 1.3756x over previous
//
#include <hip/hip_runtime.h>
#include <hip/hip_bf16.h>

#define IN_F   4096
#define OUT_F  4096
#define BATCH  256

#define EW_BLOCKS  4096
#define EW_THREADS 256
#define EW_ITERS   4   // EW_BLOCKS*EW_THREADS*4*EW_ITERS == OUT_F*IN_F

#define KSPLIT 4
#define KLEN   (IN_F / KSPLIT)   // 1024

typedef __attribute__((ext_vector_type(8))) short shortx8;    // 8 bf16
typedef __attribute__((ext_vector_type(4))) float floatx4;
typedef __attribute__((ext_vector_type(4))) unsigned short ushortx4;

typedef __attribute__((address_space(1))) const void GlbV;
typedef __attribute__((address_space(3))) void LdsV;

static __device__ __forceinline__ ushort f2bf(float f) {
    union { float f; unsigned int u; } v; v.f = f;
    unsigned int u = v.u;
    u += 0x7FFFu + ((u >> 16) & 1u);   // RNE
    return (ushort)(u >> 16);
}

static __device__ __forceinline__ float softplus_fast(float x) {
    return (x > 15.f) ? x : __logf(1.f + __expf(x));
}

#define KL_C0 (-2.80258509299f)   // log(0.1) - 0.5  (prior_sigma=0.1, prior_mu=0: spec constants)

// ---------------- Kernel 1: weight sample (bf16) + KL partial sums -----------
// (verified R6 form, unchanged)
__global__ __launch_bounds__(256) void ew_kernel(
    const float* __restrict__ mu, const float* __restrict__ rho,
    const float* __restrict__ eps,
    ushort* __restrict__ wbf, float* __restrict__ partials)
{
    const int t = blockIdx.x * EW_THREADS + threadIdx.x;
    const int STRIDE = EW_BLOCKS * EW_THREADS;

    floatx4 m[EW_ITERS], r[EW_ITERS], e[EW_ITERS];
#pragma unroll
    for (int it = 0; it < EW_ITERS; ++it) {
        const int i = t + it * STRIDE;
        m[it] = __builtin_nontemporal_load(((const floatx4*)mu) + i);
        r[it] = __builtin_nontemporal_load(((const floatx4*)rho) + i);
        e[it] = __builtin_nontemporal_load(((const floatx4*)eps) + i);
    }

    float kl = 0.f;
#pragma unroll
    for (int it = 0; it < EW_ITERS; ++it) {
        ushort w[4];
#pragma unroll
        for (int j = 0; j < 4; ++j) {
            float mm  = m[it][j];
            float sig = softplus_fast(r[it][j]);
            w[j] = f2bf(fmaf(sig, e[it][j], mm));
            kl += fmaf(50.f, fmaf(sig, sig, mm * mm), KL_C0 - __logf(sig));
        }
        ushortx4 packed = { w[0], w[1], w[2], w[3] };
        ((ushortx4*)wbf)[t + it * STRIDE] = packed;   // caching: L2/L3 holds for gemm
    }

#pragma unroll
    for (int off = 32; off; off >>= 1) kl += __shfl_down(kl, off);
    __shared__ float wsum[4];
    if ((threadIdx.x & 63) == 0) wsum[threadIdx.x >> 6] = kl;
    __syncthreads();
    if (threadIdx.x == 0)
        partials[blockIdx.x] = wsum[0] + wsum[1] + wsum[2] + wsum[3];
}

// ---------------- Kernel 1b: final KL reduction (4096 partials) --------------
__global__ __launch_bounds__(256) void kl_reduce_kernel(
    const float* __restrict__ partials, float* __restrict__ kl_out)
{
    float s = 0.f;
#pragma unroll
    for (int it = 0; it < EW_BLOCKS / 256; ++it)
        s += partials[threadIdx.x + it * 256];
#pragma unroll
    for (int off = 32; off; off >>= 1) s += __shfl_down(s, off);
    __shared__ float wsum[4];
    if ((threadIdx.x & 63) == 0) wsum[threadIdx.x >> 6] = s;
    __syncthreads();
    if (threadIdx.x == 0)
        *kl_out = wsum[0] + wsum[1] + wsum[2] + wsum[3];
}

// ---------------- Kernel 2: x f32 -> bf16 -----------------------------------
__global__ __launch_bounds__(256) void xconv_kernel(
    const float* __restrict__ x, ushort* __restrict__ xb)
{
    int i = blockIdx.x * blockDim.x + threadIdx.x;
    float4 v = ((const float4*)x)[i];
    ushortx4 o = { f2bf(v.x), f2bf(v.y), f2bf(v.z), f2bf(v.w) };
    ((ushortx4*)xb)[i] = o;
}

// ---------------- Kernel 3: split-K bf16 MFMA GEMM partials ------------------
// Verified R6 gemm structure (gload_lds + both-sides XOR swizzle), restricted
// to K-range [kz*KLEN, (kz+1)*KLEN) and storing partial C (no bias).
// Grid (64 n-tiles, 4 m-tiles, 4 kz) = 1024 blocks = 4/CU: barrier drains of
// one block overlap with compute/issue of the other three.
__global__ __launch_bounds__(256, 4) void gemm_kernel(
    const ushort* __restrict__ A, const ushort* __restrict__ B,
    float* __restrict__ Cpart)
{
    __shared__ ushort As[64 * 64];   // 8 KB, linear (swizzled content)
    __shared__ ushort Bs[64 * 64];

    const int tid  = threadIdx.x;
    const int m0   = blockIdx.y * 64;
    const int n0   = blockIdx.x * 64;
    const int kz   = blockIdx.z;
    const int kb   = kz * KLEN;
    const int wid  = tid >> 6;
    const int lane = tid & 63;
    const int wm   = wid >> 1;
    const int wn   = wid & 1;

    floatx4 acc[2][2] = {};

    const int srow  = tid >> 3;
    const int scol8 = (tid & 7) ^ (srow & 7);   // swizzled source granule
    const ushort* Ag0 = A + (size_t)(m0 + srow) * IN_F + kb + scol8 * 8;
    const ushort* Ag1 = A + (size_t)(m0 + 32 + srow) * IN_F + kb + scol8 * 8;
    const ushort* Bg0 = B + (size_t)(n0 + srow) * IN_F + kb + scol8 * 8;
    const ushort* Bg1 = B + (size_t)(n0 + 32 + srow) * IN_F + kb + scol8 * 8;
    char* AsB = (char*)As + (tid & 192) * 16;   // wave-uniform dest base
    char* BsB = (char*)Bs + (tid & 192) * 16;

    const int hi = lane >> 4;
    const int lr = lane & 15;
    const int lx = lr & 7;

    for (int k0 = 0; k0 < KLEN; k0 += 64) {
        __syncthreads();
        __builtin_amdgcn_global_load_lds((GlbV*)(Ag0 + k0), (LdsV*)(AsB),        16, 0, 0);
        __builtin_amdgcn_global_load_lds((GlbV*)(Ag1 + k0), (LdsV*)(AsB + 4096), 16, 0, 0);
        __builtin_amdgcn_global_load_lds((GlbV*)(Bg0 + k0), (LdsV*)(BsB),        16, 0, 0);
        __builtin_amdgcn_global_load_lds((GlbV*)(Bg1 + k0), (LdsV*)(BsB + 4096), 16, 0, 0);
        __syncthreads();
#pragma unroll
        for (int s = 0; s < 2; ++s) {
            const int kkq = s * 4 + hi;
            const int cs  = ((kkq ^ lx) << 4);
            shortx8 af[2], bfr[2];
#pragma unroll
            for (int i = 0; i < 2; ++i) {
                const int rowA = wm * 32 + i * 16 + lr;
                af[i] = *(const shortx8*)((char*)As + rowA * 128 + cs);
            }
#pragma unroll
            for (int j = 0; j < 2; ++j) {
                const int rowB = wn * 32 + j * 16 + lr;
                bfr[j] = *(const shortx8*)((char*)Bs + rowB * 128 + cs);
            }
#pragma unroll
            for (int i = 0; i < 2; ++i)
#pragma unroll
                for (int j = 0; j < 2; ++j)
                    acc[i][j] = __builtin_amdgcn_mfma_f32_16x16x32_bf16(
                        af[i], bfr[j], acc[i][j], 0, 0, 0);
        }
    }

    // partial-C store
    float* Cp = Cpart + (size_t)kz * BATCH * OUT_F;
#pragma unroll
    for (int j = 0; j < 2; ++j) {
        const int nn = n0 + wn * 32 + j * 16 + lr;
#pragma unroll
        for (int i = 0; i < 2; ++i) {
            const int mbase = m0 + wm * 32 + i * 16 + hi * 4;
#pragma unroll
            for (int q = 0; q < 4; ++q)
                Cp[(size_t)(mbase + q) * OUT_F + nn] = acc[i][j][q];
        }
    }
}

// ---------------- Kernel 4: combine partials + bias --------------------------
// (verified R8 form, unchanged)
__global__ __launch_bounds__(256) void combine_kernel(
    const float* __restrict__ Cpart,
    const float* __restrict__ bias_mu, const float* __restrict__ bias_rho,
    const float* __restrict__ eps_b, float* __restrict__ out)
{
    const int i  = blockIdx.x * 256 + threadIdx.x;
    const size_t NP = (size_t)BATCH * OUT_F;
    floatx4 s = ((const floatx4*)Cpart)[i];
    s += ((const floatx4*)(Cpart + NP))[i];
    s += ((const floatx4*)(Cpart + 2 * NP))[i];
    s += ((const floatx4*)(Cpart + 3 * NP))[i];
    const int o = (i * 4) & (OUT_F - 1);
    floatx4 bm = *(const floatx4*)(bias_mu + o);
    floatx4 br = *(const floatx4*)(bias_rho + o);
    floatx4 be = *(const floatx4*)(eps_b + o);
    floatx4 r;
#pragma unroll
    for (int j = 0; j < 4; ++j)
        r[j] = s[j] + fmaf(softplus_fast(br[j]), be[j], bm[j]);
    ((floatx4*)out)[i] = r;
}

extern "C" void kernel_launch(void* const* d_in, const int* in_sizes, int n_in,
                              void* d_out, int out_size, void* d_ws, size_t ws_size,
                              hipStream_t stream) {
    const float* x     = (const float*)d_in[0];
    const float* w_mu  = (const float*)d_in[1];
    const float* w_rho = (const float*)d_in[2];
    const float* b_mu  = (const float*)d_in[3];
    const float* b_rho = (const float*)d_in[4];
    const float* eps_w = (const float*)d_in[5];
    const float* eps_b = (const float*)d_in[6];
    // d_in[7]=prior_mu (zeros), d_in[8]=prior_sigma (0.1): folded constants.

    float* out = (float*)d_out;
    const size_t KL_IDX = (size_t)BATCH * OUT_F;

    ushort* w_bf     = (ushort*)d_ws;                                     // 32 MB
    ushort* x_bf     = (ushort*)((char*)d_ws + (size_t)OUT_F * IN_F * 2); // 2 MB
    float*  Cpart    = (float*)((char*)x_bf + (size_t)BATCH * IN_F * 2);  // 16 MB
    float*  partials = (float*)((char*)Cpart
                         + (size_t)KSPLIT * BATCH * OUT_F * 4);           // 16 KB

    // weight sample + KL partials (NT input streams)
    ew_kernel<<<EW_BLOCKS, EW_THREADS, 0, stream>>>(
        w_mu, w_rho, eps_w, w_bf, partials);
    // x -> bf16
    xconv_kernel<<<(BATCH * IN_F / 4) / 256, 256, 0, stream>>>(x, x_bf);
    // split-K GEMM partials (1024 blocks = 4/CU)
    dim3 grid(OUT_F / 64, BATCH / 64, KSPLIT);
    gemm_kernel<<<grid, 256, 0, stream>>>(x_bf, w_bf, Cpart);
    // combine + bias
    combine_kernel<<<(BATCH * OUT_F / 4) / 256, 256, 0, stream>>>(
        Cpart, b_mu, b_rho, eps_b, out);
    // final KL
    kl_reduce_kernel<<<1, 256, 0, stream>>>(partials, out + KL_IDX);
}

// Round 10
// 71.499 us; speedup vs baseline: 1.3991x; 1.0171x over previous
//
#include <hip/hip_runtime.h>
#include <hip/hip_bf16.h>

#define IN_F   4096
#define OUT_F  4096
#define BATCH  256

#define EW_BLOCKS  4096
#define EW_THREADS 256
#define EW_ITERS   4   // EW_BLOCKS*EW_THREADS*4*EW_ITERS == OUT_F*IN_F

#define KSPLIT 4
#define KLEN   (IN_F / KSPLIT)   // 1024

typedef __attribute__((ext_vector_type(8))) short shortx8;    // 8 bf16
typedef __attribute__((ext_vector_type(4))) float floatx4;
typedef __attribute__((ext_vector_type(4))) unsigned short ushortx4;

typedef __attribute__((address_space(1))) const void GlbV;
typedef __attribute__((address_space(3))) void LdsV;

static __device__ __forceinline__ ushort f2bf(float f) {
    union { float f; unsigned int u; } v; v.f = f;
    unsigned int u = v.u;
    u += 0x7FFFu + ((u >> 16) & 1u);   // RNE
    return (ushort)(u >> 16);
}

static __device__ __forceinline__ float softplus_fast(float x) {
    return (x > 15.f) ? x : __logf(1.f + __expf(x));
}

#define KL_C0 (-2.80258509299f)   // log(0.1) - 0.5  (prior_sigma=0.1, prior_mu=0: spec constants)

// ---------------- Kernel 1: weight sample (bf16) + KL partial sums -----------
// sched_barrier(0) after the load block: scheduler may not sink the 12 NT
// loads toward their uses -> all 12 stay in flight (fixes the VGPR=36 tell).
__global__ __launch_bounds__(256) void ew_kernel(
    const float* __restrict__ mu, const float* __restrict__ rho,
    const float* __restrict__ eps,
    ushort* __restrict__ wbf, float* __restrict__ partials)
{
    const int t = blockIdx.x * EW_THREADS + threadIdx.x;
    const int STRIDE = EW_BLOCKS * EW_THREADS;

    floatx4 m[EW_ITERS], r[EW_ITERS], e[EW_ITERS];
#pragma unroll
    for (int it = 0; it < EW_ITERS; ++it) {
        const int i = t + it * STRIDE;
        m[it] = __builtin_nontemporal_load(((const floatx4*)mu) + i);
        r[it] = __builtin_nontemporal_load(((const floatx4*)rho) + i);
        e[it] = __builtin_nontemporal_load(((const floatx4*)eps) + i);
    }
    __builtin_amdgcn_sched_barrier(0);   // loads stay hoisted above this line

    float kl = 0.f;
#pragma unroll
    for (int it = 0; it < EW_ITERS; ++it) {
        ushort w[4];
#pragma unroll
        for (int j = 0; j < 4; ++j) {
            float mm  = m[it][j];
            float sig = softplus_fast(r[it][j]);
            w[j] = f2bf(fmaf(sig, e[it][j], mm));
            kl += fmaf(50.f, fmaf(sig, sig, mm * mm), KL_C0 - __logf(sig));
        }
        ushortx4 packed = { w[0], w[1], w[2], w[3] };
        ((ushortx4*)wbf)[t + it * STRIDE] = packed;   // caching: L2/L3 holds for gemm
    }

#pragma unroll
    for (int off = 32; off; off >>= 1) kl += __shfl_down(kl, off);
    __shared__ float wsum[4];
    if ((threadIdx.x & 63) == 0) wsum[threadIdx.x >> 6] = kl;
    __syncthreads();
    if (threadIdx.x == 0)
        partials[blockIdx.x] = wsum[0] + wsum[1] + wsum[2] + wsum[3];
}

// ---------------- Kernel 2: x f32 -> bf16 -----------------------------------
__global__ __launch_bounds__(256) void xconv_kernel(
    const float* __restrict__ x, ushort* __restrict__ xb)
{
    int i = blockIdx.x * blockDim.x + threadIdx.x;
    float4 v = ((const float4*)x)[i];
    ushortx4 o = { f2bf(v.x), f2bf(v.y), f2bf(v.z), f2bf(v.w) };
    ((ushortx4*)xb)[i] = o;
}

// ---------------- Kernel 3: split-K bf16 MFMA GEMM partials ------------------
// (verified R9 form, unchanged)
__global__ __launch_bounds__(256, 4) void gemm_kernel(
    const ushort* __restrict__ A, const ushort* __restrict__ B,
    float* __restrict__ Cpart)
{
    __shared__ ushort As[64 * 64];   // 8 KB, linear (swizzled content)
    __shared__ ushort Bs[64 * 64];

    const int tid  = threadIdx.x;
    const int m0   = blockIdx.y * 64;
    const int n0   = blockIdx.x * 64;
    const int kz   = blockIdx.z;
    const int kb   = kz * KLEN;
    const int wid  = tid >> 6;
    const int lane = tid & 63;
    const int wm   = wid >> 1;
    const int wn   = wid & 1;

    floatx4 acc[2][2] = {};

    const int srow  = tid >> 3;
    const int scol8 = (tid & 7) ^ (srow & 7);   // swizzled source granule
    const ushort* Ag0 = A + (size_t)(m0 + srow) * IN_F + kb + scol8 * 8;
    const ushort* Ag1 = A + (size_t)(m0 + 32 + srow) * IN_F + kb + scol8 * 8;
    const ushort* Bg0 = B + (size_t)(n0 + srow) * IN_F + kb + scol8 * 8;
    const ushort* Bg1 = B + (size_t)(n0 + 32 + srow) * IN_F + kb + scol8 * 8;
    char* AsB = (char*)As + (tid & 192) * 16;   // wave-uniform dest base
    char* BsB = (char*)Bs + (tid & 192) * 16;

    const int hi = lane >> 4;
    const int lr = lane & 15;
    const int lx = lr & 7;

    for (int k0 = 0; k0 < KLEN; k0 += 64) {
        __syncthreads();
        __builtin_amdgcn_global_load_lds((GlbV*)(Ag0 + k0), (LdsV*)(AsB),        16, 0, 0);
        __builtin_amdgcn_global_load_lds((GlbV*)(Ag1 + k0), (LdsV*)(AsB + 4096), 16, 0, 0);
        __builtin_amdgcn_global_load_lds((GlbV*)(Bg0 + k0), (LdsV*)(BsB),        16, 0, 0);
        __builtin_amdgcn_global_load_lds((GlbV*)(Bg1 + k0), (LdsV*)(BsB + 4096), 16, 0, 0);
        __syncthreads();
#pragma unroll
        for (int s = 0; s < 2; ++s) {
            const int kkq = s * 4 + hi;
            const int cs  = ((kkq ^ lx) << 4);
            shortx8 af[2], bfr[2];
#pragma unroll
            for (int i = 0; i < 2; ++i) {
                const int rowA = wm * 32 + i * 16 + lr;
                af[i] = *(const shortx8*)((char*)As + rowA * 128 + cs);
            }
#pragma unroll
            for (int j = 0; j < 2; ++j) {
                const int rowB = wn * 32 + j * 16 + lr;
                bfr[j] = *(const shortx8*)((char*)Bs + rowB * 128 + cs);
            }
#pragma unroll
            for (int i = 0; i < 2; ++i)
#pragma unroll
                for (int j = 0; j < 2; ++j)
                    acc[i][j] = __builtin_amdgcn_mfma_f32_16x16x32_bf16(
                        af[i], bfr[j], acc[i][j], 0, 0, 0);
        }
    }

    // partial-C store
    float* Cp = Cpart + (size_t)kz * BATCH * OUT_F;
#pragma unroll
    for (int j = 0; j < 2; ++j) {
        const int nn = n0 + wn * 32 + j * 16 + lr;
#pragma unroll
        for (int i = 0; i < 2; ++i) {
            const int mbase = m0 + wm * 32 + i * 16 + hi * 4;
#pragma unroll
            for (int q = 0; q < 4; ++q)
                Cp[(size_t)(mbase + q) * OUT_F + nn] = acc[i][j][q];
        }
    }
}

// ---------------- Kernel 4: combine partials + bias + final KL ---------------
// Block 0 additionally reduces the 4096 ew partials -> kl_out (saves a launch).
__global__ __launch_bounds__(256) void combine_kernel(
    const float* __restrict__ Cpart,
    const float* __restrict__ bias_mu, const float* __restrict__ bias_rho,
    const float* __restrict__ eps_b, float* __restrict__ out,
    const float* __restrict__ partials, float* __restrict__ kl_out)
{
    const int i  = blockIdx.x * 256 + threadIdx.x;
    const size_t NP = (size_t)BATCH * OUT_F;
    floatx4 s = __builtin_nontemporal_load(((const floatx4*)Cpart) + i);
    s += __builtin_nontemporal_load(((const floatx4*)(Cpart + NP)) + i);
    s += __builtin_nontemporal_load(((const floatx4*)(Cpart + 2 * NP)) + i);
    s += __builtin_nontemporal_load(((const floatx4*)(Cpart + 3 * NP)) + i);
    const int o = (i * 4) & (OUT_F - 1);
    floatx4 bm = *(const floatx4*)(bias_mu + o);
    floatx4 br = *(const floatx4*)(bias_rho + o);
    floatx4 be = *(const floatx4*)(eps_b + o);
    floatx4 r;
#pragma unroll
    for (int j = 0; j < 4; ++j)
        r[j] = s[j] + fmaf(softplus_fast(br[j]), be[j], bm[j]);
    ((floatx4*)out)[i] = r;

    if (blockIdx.x == 0) {
        float kl = 0.f;
#pragma unroll
        for (int it = 0; it < EW_BLOCKS / 256; ++it)
            kl += partials[threadIdx.x + it * 256];
#pragma unroll
        for (int off = 32; off; off >>= 1) kl += __shfl_down(kl, off);
        __shared__ float wsum[4];
        if ((threadIdx.x & 63) == 0) wsum[threadIdx.x >> 6] = kl;
        __syncthreads();
        if (threadIdx.x == 0)
            *kl_out = wsum[0] + wsum[1] + wsum[2] + wsum[3];
    }
}

extern "C" void kernel_launch(void* const* d_in, const int* in_sizes, int n_in,
                              void* d_out, int out_size, void* d_ws, size_t ws_size,
                              hipStream_t stream) {
    const float* x     = (const float*)d_in[0];
    const float* w_mu  = (const float*)d_in[1];
    const float* w_rho = (const float*)d_in[2];
    const float* b_mu  = (const float*)d_in[3];
    const float* b_rho = (const float*)d_in[4];
    const float* eps_w = (const float*)d_in[5];
    const float* eps_b = (const float*)d_in[6];
    // d_in[7]=prior_mu (zeros), d_in[8]=prior_sigma (0.1): folded constants.

    float* out = (float*)d_out;
    const size_t KL_IDX = (size_t)BATCH * OUT_F;

    ushort* w_bf     = (ushort*)d_ws;                                     // 32 MB
    ushort* x_bf     = (ushort*)((char*)d_ws + (size_t)OUT_F * IN_F * 2); // 2 MB
    float*  Cpart    = (float*)((char*)x_bf + (size_t)BATCH * IN_F * 2);  // 16 MB
    float*  partials = (float*)((char*)Cpart
                         + (size_t)KSPLIT * BATCH * OUT_F * 4);           // 16 KB

    // weight sample + KL partials (NT input streams, loads fenced hoisted)
    ew_kernel<<<EW_BLOCKS, EW_THREADS, 0, stream>>>(
        w_mu, w_rho, eps_w, w_bf, partials);
    // x -> bf16
    xconv_kernel<<<(BATCH * IN_F / 4) / 256, 256, 0, stream>>>(x, x_bf);
    // split-K GEMM partials (1024 blocks = 4/CU)
    dim3 grid(OUT_F / 64, BATCH / 64, KSPLIT);
    gemm_kernel<<<grid, 256, 0, stream>>>(x_bf, w_bf, Cpart);
    // combine + bias + final KL
    combine_kernel<<<(BATCH * OUT_F / 4) / 256, 256, 0, stream>>>(
        Cpart, b_mu, b_rho, eps_b, out, partials, out + KL_IDX);
}